// Round 5
// baseline (264.275 us; speedup 1.0000x reference)
//
// round 4 resubmission — identical logic to round 0 baseline (infra failures r1-r4)
#include <hip/hip_runtime.h>
#include <hip/hip_bf16.h>

#define NV 300000
#define CH 32
#define KK 27

typedef __attribute__((ext_vector_type(8))) short bf16x8;
typedef __attribute__((ext_vector_type(4))) float f32x4;

// ws layout (bytes)
#define XB_OFF   0u
#define XB_BYTES 19200128u            // (NV+1)*CH*2 = 19200064, padded
#define HB_OFF   19200128u
#define W0T_OFF  38400256u            // KK*CH*CH*2 = 55296
#define W1T_OFF  38455552u
// total ~38.5 MB

__device__ __forceinline__ unsigned short f2b(float f) {
    unsigned int u = __builtin_bit_cast(unsigned int, f);
    unsigned int r = (u + 0x7FFFu + ((u >> 16) & 1u)) >> 16;
    return (unsigned short)r;
}

// --- prep: x -> bf16 (+pad row), zero h pad row, transpose weights to [k][d][c] bf16
__global__ __launch_bounds__(256) void prep_kernel(
    const float* __restrict__ x,
    const float* __restrict__ w0,
    const float* __restrict__ w1,
    unsigned short* __restrict__ xb,   // (NV+1)*CH
    unsigned short* __restrict__ hb,   // (NV+1)*CH (only pad row touched here)
    unsigned short* __restrict__ w0t,
    unsigned short* __restrict__ w1t)
{
    const int NX = NV * CH / 8;  // 1,200,000 threads: 8 elems each
    int tid = blockIdx.x * blockDim.x + threadIdx.x;
    if (tid < NX) {
        int base = tid * 8;
        const float4* p = reinterpret_cast<const float4*>(x + base);
        float4 a = p[0], b = p[1];
        union { unsigned short u[8]; bf16x8 v; } pk;
        pk.u[0] = f2b(a.x); pk.u[1] = f2b(a.y); pk.u[2] = f2b(a.z); pk.u[3] = f2b(a.w);
        pk.u[4] = f2b(b.x); pk.u[5] = f2b(b.y); pk.u[6] = f2b(b.z); pk.u[7] = f2b(b.w);
        *reinterpret_cast<bf16x8*>(xb + base) = pk.v;
        return;
    }
    int t = tid - NX;
    if (t < 4) {  // zero xb pad row (row NV), 8 elems each
        union { unsigned short u[8]; bf16x8 v; } z; 
        for (int j = 0; j < 8; ++j) z.u[j] = 0;
        *reinterpret_cast<bf16x8*>(xb + NV * CH + t * 8) = z.v;
        return;
    }
    t -= 4;
    if (t < 4) {  // zero hb pad row
        union { unsigned short u[8]; bf16x8 v; } z;
        for (int j = 0; j < 8; ++j) z.u[j] = 0;
        *reinterpret_cast<bf16x8*>(hb + NV * CH + t * 8) = z.v;
        return;
    }
    t -= 4;
    if (t < 2 * KK * CH * CH) {  // weight transpose: wt[k][d][c] = w[k][c][d]
        int which = t >= KK * CH * CH;
        int e = t - which * KK * CH * CH;
        int k = e / (CH * CH);
        int rem = e - k * (CH * CH);
        int d = rem / CH;
        int c = rem - d * CH;
        const float* w = which ? w1 : w0;
        unsigned short* o = which ? w1t : w0t;
        o[e] = f2b(w[k * CH * CH + c * CH + d]);
    }
}

// --- conv layer: per wave, 16 output rows; GEMM over K=27*32 via mfma 16x16x32 bf16
template <bool FIRST>
__global__ __launch_bounds__(256) void conv_kernel(
    const unsigned short* __restrict__ in_b,  // (NV+1)*CH bf16
    const int* __restrict__ nbr,              // KK*NV
    const unsigned short* __restrict__ wt,    // KK*CH*CH bf16, [k][d][c]
    const float* __restrict__ bias,           // CH
    const float* __restrict__ xres,           // NV*CH f32 (layer2 residual) or null
    unsigned short* __restrict__ out_b,       // layer1 out (bf16)
    float* __restrict__ out_f)                // layer2 out (f32)
{
    const int wave = (blockIdx.x * blockDim.x + threadIdx.x) >> 6;
    if (wave >= NV / 16) return;
    const int lane = threadIdx.x & 63;
    const int r = lane & 15;     // A row in tile / D col
    const int g = lane >> 4;     // 0..3 : k-group
    const int row0 = wave * 16;
    const int i = row0 + r;

    f32x4 acc0 = {0.f, 0.f, 0.f, 0.f};
    f32x4 acc1 = {0.f, 0.f, 0.f, 0.f};

    const unsigned short* bp0 = wt + r * CH + g * 8;
    const unsigned short* bp1 = wt + (r + 16) * CH + g * 8;

#pragma unroll
    for (int k = 0; k < KK; ++k) {
        int idx = nbr[k * NV + i];
        bf16x8 a  = *reinterpret_cast<const bf16x8*>(in_b + idx * CH + g * 8);
        bf16x8 b0 = *reinterpret_cast<const bf16x8*>(bp0 + k * CH * CH);
        bf16x8 b1 = *reinterpret_cast<const bf16x8*>(bp1 + k * CH * CH);
        acc0 = __builtin_amdgcn_mfma_f32_16x16x32_bf16(a, b0, acc0, 0, 0, 0);
        acc1 = __builtin_amdgcn_mfma_f32_16x16x32_bf16(a, b1, acc1, 0, 0, 0);
    }

    const float bs0 = bias[r];
    const float bs1 = bias[r + 16];
#pragma unroll
    for (int j = 0; j < 4; ++j) {
        int row = row0 + g * 4 + j;
        float v0 = acc0[j] + bs0;
        float v1 = acc1[j] + bs1;
        if (FIRST) {
            v0 = fmaxf(v0, 0.f);
            v1 = fmaxf(v1, 0.f);
            out_b[row * CH + r]      = f2b(v0);
            out_b[row * CH + r + 16] = f2b(v1);
        } else {
            out_f[row * CH + r]      = v0 + xres[row * CH + r];
            out_f[row * CH + r + 16] = v1 + xres[row * CH + r + 16];
        }
    }
}

extern "C" void kernel_launch(void* const* d_in, const int* in_sizes, int n_in,
                              void* d_out, int out_size, void* d_ws, size_t ws_size,
                              hipStream_t stream) {
    const float* x   = (const float*)d_in[0];
    const int* nbr   = (const int*)d_in[1];
    const float* w0  = (const float*)d_in[2];
    const float* b0  = (const float*)d_in[3];
    const float* w1  = (const float*)d_in[4];
    const float* b1  = (const float*)d_in[5];
    float* out = (float*)d_out;

    char* ws = (char*)d_ws;
    unsigned short* xb  = (unsigned short*)(ws + XB_OFF);
    unsigned short* hb  = (unsigned short*)(ws + HB_OFF);
    unsigned short* w0t = (unsigned short*)(ws + W0T_OFF);
    unsigned short* w1t = (unsigned short*)(ws + W1T_OFF);

    // prep
    {
        int total = NV * CH / 8 + 8 + 2 * KK * CH * CH;  // 1,255,304
        int blocks = (total + 255) / 256;
        prep_kernel<<<blocks, 256, 0, stream>>>(x, w0, w1, xb, hb, w0t, w1t);
    }
    // conv layers: one wave per 16 rows
    int waves = NV / 16;                 // 18750
    int blocks = (waves + 3) / 4;        // 256 threads = 4 waves
    conv_kernel<true><<<blocks, 256, 0, stream>>>(xb, nbr, w0t, b0, nullptr, hb, nullptr);
    conv_kernel<false><<<blocks, 256, 0, stream>>>(hb, nbr, w1t, b1, x, nullptr, out);
}